// Round 1
// baseline (149.684 us; speedup 1.0000x reference)
//
#include <hip/hip_runtime.h>

// IDWT3D (haar, tiny): out[T,H,W,c] = x[T/2,H/2,W/2,c] * (1/sqrt(2))^3
// x: (16,128,128,64) f32 -> out: (32,256,256,64) f32
// Pure memory-bound upsample; one float4 of output per thread-iteration.

__global__ void idwt3_haar_upsample(const float4* __restrict__ in,
                                    float4* __restrict__ out,
                                    int total4) {
    const float s = 0.35355339059327379f;  // (1/sqrt2)^3
    int idx = blockIdx.x * blockDim.x + threadIdx.x;
    int stride = gridDim.x * blockDim.x;
    for (int i = idx; i < total4; i += stride) {
        // out float4 index i: c4 = i & 15 (16 float4 per voxel, c=64)
        //                     W  = (i>>4)  & 255
        //                     H  = (i>>12) & 255
        //                     T  =  i>>20          (0..31)
        int c4 = i & 15;
        int w  = (i >> 4) & 255;
        int h  = (i >> 12) & 255;
        int t  = i >> 20;
        // input float4 index: ((t/2)*128*128 + (h/2)*128 + (w/2)) * 16 + c4
        int src = ((t >> 1) << 18) + ((h >> 1) << 11) + ((w >> 1) << 4) + c4;
        float4 v = in[src];
        v.x *= s; v.y *= s; v.z *= s; v.w *= s;
        out[i] = v;
    }
}

extern "C" void kernel_launch(void* const* d_in, const int* in_sizes, int n_in,
                              void* d_out, int out_size, void* d_ws, size_t ws_size,
                              hipStream_t stream) {
    const float4* in = (const float4*)d_in[0];
    float4* out = (float4*)d_out;
    int total4 = out_size / 4;  // 33,554,432 float4
    int block = 256;
    int grid = 2048;            // grid-stride; 256 CU * 8 blocks
    idwt3_haar_upsample<<<grid, block, 0, stream>>>(in, out, total4);
}

// Round 3
// 116.130 us; speedup vs baseline: 1.2889x; 1.2889x over previous
//
#include <hip/hip_runtime.h>

// IDWT3D (haar, tiny): out[T,H,W,c] = x[T/2,H/2,W/2,c] * (1/sqrt2)^3
// x: (16,128,128,64) f32 -> out: (32,256,256,64) f32
// Gather->scatter inversion: each thread loads ONE input float4 (read-once,
// FETCH == 64 MiB exactly) and writes its 8 upsample duplicates with
// nontemporal stores (output is write-once; skip L2/L3 allocation).
// Uses clang native vector type (__builtin_nontemporal_store rejects
// HIP_vector_type classes).
//
// Output f4 index (T,H,W,c4) = (T<<20) + (H<<12) + (W<<4) + c4
// Input  f4 index (t,h,w,c4) = (t<<18) + (h<<11) + (w<<4) + c4

typedef float f4 __attribute__((ext_vector_type(4)));

__global__ void idwt3_haar_scatter(const f4* __restrict__ in,
                                   f4* __restrict__ out,
                                   int nin4) {
    const float s = 0.35355339059327379f;  // (1/sqrt2)^3
    int idx = blockIdx.x * blockDim.x + threadIdx.x;
    int stride = gridDim.x * blockDim.x;
    for (int v = idx; v < nin4; v += stride) {
        int c4 = v & 15;
        int w  = (v >> 4) & 127;
        int h  = (v >> 11) & 127;
        int t  = v >> 18;
        f4 x = __builtin_nontemporal_load(in + v);
        x *= s;
        // base = output index of (2t, 2h, 2w, c4)
        int base = (t << 21) + (h << 13) + (w << 5) + c4;
        f4* p0 = out + base;                         // (2t, 2h,   2w)
        f4* p1 = out + base + (1 << 12);             // (2t, 2h+1, 2w)
        f4* p2 = out + base + (1 << 20);             // (2t+1, 2h,   2w)
        f4* p3 = out + base + (1 << 20) + (1 << 12); // (2t+1, 2h+1, 2w)
        __builtin_nontemporal_store(x, p0);
        __builtin_nontemporal_store(x, p0 + 16);     // W+1
        __builtin_nontemporal_store(x, p1);
        __builtin_nontemporal_store(x, p1 + 16);
        __builtin_nontemporal_store(x, p2);
        __builtin_nontemporal_store(x, p2 + 16);
        __builtin_nontemporal_store(x, p3);
        __builtin_nontemporal_store(x, p3 + 16);
    }
}

extern "C" void kernel_launch(void* const* d_in, const int* in_sizes, int n_in,
                              void* d_out, int out_size, void* d_ws, size_t ws_size,
                              hipStream_t stream) {
    const f4* in = (const f4*)d_in[0];
    f4* out = (f4*)d_out;
    int nin4 = in_sizes[0] / 4;  // 4,194,304 input float4
    int block = 256;
    int grid = 2048;             // grid-stride, 8 iters/thread
    idwt3_haar_scatter<<<grid, block, 0, stream>>>(in, out, nin4);
}

// Round 4
// 92.731 us; speedup vs baseline: 1.6142x; 1.2523x over previous
//
#include <hip/hip_runtime.h>

// IDWT3D (haar, tiny): out[T,H,W,c] = x[T/2,H/2,W/2,c] * (1/sqrt2)^3
// x: (16,128,128,64) f32 -> out: (32,256,256,64) f32
// Gather->scatter: each thread loads ONE input float4, writes its 8 upsample
// duplicates. Loads are TEMPORAL (input = 64 MiB, L3-resident across graph
// replays -> steady-state HBM traffic is write-only). Stores are NONTEMPORAL
// (512 MiB write-once stream; no L2/L3 allocation, so it can't evict the
// input from L3).
//
// Output f4 index (T,H,W,c4) = (T<<20) + (H<<12) + (W<<4) + c4
// Input  f4 index (t,h,w,c4) = (t<<18) + (h<<11) + (w<<4) + c4

typedef float f4 __attribute__((ext_vector_type(4)));

__global__ void idwt3_haar_scatter(const f4* __restrict__ in,
                                   f4* __restrict__ out,
                                   int nin4) {
    const float s = 0.35355339059327379f;  // (1/sqrt2)^3
    int idx = blockIdx.x * blockDim.x + threadIdx.x;
    int stride = gridDim.x * blockDim.x;
    for (int v = idx; v < nin4; v += stride) {
        int c4 = v & 15;
        int w  = (v >> 4) & 127;
        int h  = (v >> 11) & 127;
        int t  = v >> 18;
        f4 x = in[v];          // temporal: allocate in L2/L3, reused across replays
        x *= s;
        // base = output index of (2t, 2h, 2w, c4)
        int base = (t << 21) + (h << 13) + (w << 5) + c4;
        f4* p0 = out + base;                         // (2t,   2h,   2w)
        f4* p1 = out + base + (1 << 12);             // (2t,   2h+1, 2w)
        f4* p2 = out + base + (1 << 20);             // (2t+1, 2h,   2w)
        f4* p3 = out + base + (1 << 20) + (1 << 12); // (2t+1, 2h+1, 2w)
        __builtin_nontemporal_store(x, p0);
        __builtin_nontemporal_store(x, p0 + 16);     // W+1
        __builtin_nontemporal_store(x, p1);
        __builtin_nontemporal_store(x, p1 + 16);
        __builtin_nontemporal_store(x, p2);
        __builtin_nontemporal_store(x, p2 + 16);
        __builtin_nontemporal_store(x, p3);
        __builtin_nontemporal_store(x, p3 + 16);
    }
}

extern "C" void kernel_launch(void* const* d_in, const int* in_sizes, int n_in,
                              void* d_out, int out_size, void* d_ws, size_t ws_size,
                              hipStream_t stream) {
    const f4* in = (const f4*)d_in[0];
    f4* out = (f4*)d_out;
    int nin4 = in_sizes[0] / 4;  // 4,194,304 input float4
    int block = 256;
    int grid = 2048;             // grid-stride, 8 iters/thread
    idwt3_haar_scatter<<<grid, block, 0, stream>>>(in, out, nin4);
}